// Round 2
// baseline (254.961 us; speedup 1.0000x reference)
//
#include <hip/hip_runtime.h>

// I/O: float32 (per reference). Internal compute: bf16 MFMA (2%-relative
// threshold; measured absmax 0.0156 vs 0.0615 budget in R2/R3).
//
// R6: concurrency re-tile. R5 counters: fused_mlp 92.6us with MfmaUtil 21%,
// VALUBusy 19%, HBM 27%, LDS-pipe ~28% -- nothing saturated => latency-bound
// at 2 blocks/CU (66.5KB LDS, 37% occupancy; barriers covered by only 1
// other block). Also WRITE_SIZE 181.5MB vs 151MB ideal (partial-128B-line
// nontemporal stores). Now: 32-token x 256-thread blocks, 1024 blocks =
// exactly 4 blocks/CU (4 barrier domains/CU). Wave owns 2 token-tiles x 288
// cols: LDS b128 A-reads halve (224->112/wave, the conflicted pipe); weight
// loads double (L2-resident, the idle pipe). Per (wave,gi) stores cover
// 384B = 3 full 128B lines per token row, 128B-aligned -> amplification
// gone, nontemporal safe.

typedef __attribute__((ext_vector_type(4))) float  floatx4;
typedef __attribute__((ext_vector_type(8))) short  shortx8;
typedef __attribute__((ext_vector_type(4))) short  shortx4;

__device__ __forceinline__ short f2bf(float f) {
    unsigned u = __builtin_bit_cast(unsigned, f);
    u += 0x7fffu + ((u >> 16) & 1u);   // RTNE
    return (short)(u >> 16);
}

__device__ __forceinline__ shortx8 cvt8(const float* __restrict__ p) {
    floatx4 a = *(const floatx4*)p;
    floatx4 b = *(const floatx4*)(p + 4);
    shortx8 r;
    r[0] = f2bf(a[0]); r[1] = f2bf(a[1]); r[2] = f2bf(a[2]); r[3] = f2bf(a[3]);
    r[4] = f2bf(b[0]); r[5] = f2bf(b[1]); r[6] = f2bf(b[2]); r[7] = f2bf(b[3]);
    return r;
}

// Single-launch repack of W1/W2/W3 (f32 row-major [K,N]) into bf16 MFMA
// fragment order. Tile rel=(nt*KT+kt): lane l holds
// W[kt*32+(l>>4)*8+j][nt*16+(l&15)], j=0..7, 16B contiguous per lane.
// (Used as the A operand: mfma(w_frag, x_frag) computes the transposed tile,
// so D reg index runs along contiguous output columns.)
__global__ void repack_all(const float* __restrict__ W1,
                           const float* __restrict__ W2,
                           const float* __restrict__ W3,
                           short* __restrict__ ws) {
    int t = blockIdx.x * blockDim.x + threadIdx.x;
    int tile = t >> 6, lane = t & 63;
    const float* src; short* dst; int N, KT, rel;
    if (tile < 192)       { src = W1; dst = ws;                  N = 256;  KT = 12; rel = tile; }
    else if (tile < 448)  { src = W2; dst = ws + 98304;          N = 512;  KT = 8;  rel = tile - 192; }
    else if (tile < 1600) { src = W3; dst = ws + 98304 + 131072; N = 1152; KT = 16; rel = tile - 448; }
    else return;
    int nt = rel / KT, kt = rel - nt * KT;
    int col  = nt * 16 + (lane & 15);
    int row0 = kt * 32 + (lane >> 4) * 8;
    shortx8 v;
#pragma unroll
    for (int j = 0; j < 8; ++j) v[j] = f2bf(src[(row0 + j) * N + col]);
    *(shortx8*)(dst + rel * 512 + lane * 8) = v;
}

__global__ __launch_bounds__(256, 4) void fused_mlp(
    const float* __restrict__ content, const float* __restrict__ motion,
    const float* __restrict__ b1, const float* __restrict__ b2,
    const float* __restrict__ b3,
    const short* __restrict__ w1p, const short* __restrict__ w2p,
    const short* __restrict__ w3p, float* __restrict__ out)
{
    __shared__ short hbuf[32 * 520];   // 33,280 B: h2 view stride 520; h1 view stride 264

    const int tid  = threadIdx.x;
    const int lane = tid & 63;
    const int w    = tid >> 6;        // wave 0..3: output-column-strip owner
    const int l15  = lane & 15;
    const int q    = lane >> 4;       // 0..3
    const int m0   = blockIdx.x * 32;
    const int bidx = blockIdx.x >> 4; // batch element (16 blocks per batch row)

    // ---------------- Layer 1: X[32,384] @ W1 -> h1[32,256] ----------------
    {
        floatx4 accC[4]    = {};      // content contribution (token-independent)
        floatx4 accM[2][4] = {};      // motion contribution per token tile
        const float* crow = content + bidx * 256;
        // content half: k = 0..255, computed ONCE (identical for all tokens)
#pragma unroll
        for (int kt = 0; kt < 8; ++kt) {
            shortx8 xb = cvt8(crow + kt * 32 + q * 8);
#pragma unroll
            for (int nt = 0; nt < 4; ++nt) {
                shortx8 wf = *(const shortx8*)(w1p + ((w * 4 + nt) * 12 + kt) * 512 + lane * 8);
                accC[nt] = __builtin_amdgcn_mfma_f32_16x16x32_bf16(wf, xb, accC[nt], 0, 0, 0);
            }
        }
        // motion half: k = 256..383
#pragma unroll
        for (int kt = 8; kt < 12; ++kt) {
            shortx8 xb[2];
#pragma unroll
            for (int tt = 0; tt < 2; ++tt)
                xb[tt] = cvt8(motion + (m0 + tt * 16 + l15) * 128 + (kt * 32 - 256) + q * 8);
#pragma unroll
            for (int nt = 0; nt < 4; ++nt) {
                shortx8 wf = *(const shortx8*)(w1p + ((w * 4 + nt) * 12 + kt) * 512 + lane * 8);
#pragma unroll
                for (int tt = 0; tt < 2; ++tt)
                    accM[tt][nt] = __builtin_amdgcn_mfma_f32_16x16x32_bf16(wf, xb[tt], accM[tt][nt], 0, 0, 0);
            }
        }
#pragma unroll
        for (int nt = 0; nt < 4; ++nt) {
            const int colb = (w * 4 + nt) * 16 + q * 4;
            const floatx4 bias = *(const floatx4*)(b1 + colb);
#pragma unroll
            for (int tt = 0; tt < 2; ++tt) {
                shortx4 pk;
#pragma unroll
                for (int r = 0; r < 4; ++r) {
                    float v = accM[tt][nt][r] + accC[nt][r] + bias[r];
                    v = (v >= 0.f) ? v : 0.2f * v;
                    pk[r] = f2bf(v);
                }
                *(shortx4*)(&hbuf[(tt * 16 + l15) * 264 + colb]) = pk;  // 8B ds_write
            }
        }
    }
    __syncthreads();

    // ---------------- Layer 2: h1[32,256] @ W2 -> h2[32,512] ----------------
    {
        floatx4 acc[2][8] = {};
#pragma unroll
        for (int kt = 0; kt < 8; ++kt) {
            shortx8 hb[2];
#pragma unroll
            for (int tt = 0; tt < 2; ++tt)
                hb[tt] = *(const shortx8*)(&hbuf[(tt * 16 + l15) * 264 + kt * 32 + q * 8]);
#pragma unroll
            for (int nt = 0; nt < 8; ++nt) {
                shortx8 wf = *(const shortx8*)(w2p + ((w * 8 + nt) * 8 + kt) * 512 + lane * 8);
#pragma unroll
                for (int tt = 0; tt < 2; ++tt)
                    acc[tt][nt] = __builtin_amdgcn_mfma_f32_16x16x32_bf16(wf, hb[tt], acc[tt][nt], 0, 0, 0);
            }
        }
        __syncthreads();   // all h1 reads complete before h2 overwrites buffer
#pragma unroll
        for (int nt = 0; nt < 8; ++nt) {
            const int colb = (w * 8 + nt) * 16 + q * 4;
            const floatx4 bias = *(const floatx4*)(b2 + colb);
#pragma unroll
            for (int tt = 0; tt < 2; ++tt) {
                shortx4 pk;
#pragma unroll
                for (int r = 0; r < 4; ++r) {
                    float v = acc[tt][nt][r] + bias[r];
                    v = (v >= 0.f) ? v : 0.2f * v;
                    pk[r] = f2bf(v);
                }
                *(shortx4*)(&hbuf[(tt * 16 + l15) * 520 + colb]) = pk;  // 8B ds_write
            }
        }
    }
    __syncthreads();

    // ----- Layer 3: h2[32,512] @ W3 -> out[32,1152], 3 passes of 96 cols/wave -----
#pragma unroll 1
    for (int gi = 0; gi < 3; ++gi) {
        floatx4 acc[2][6] = {};   // 48 accs
#pragma unroll 4
        for (int kt = 0; kt < 16; ++kt) {
            shortx8 hb[2];
#pragma unroll
            for (int tt = 0; tt < 2; ++tt)
                hb[tt] = *(const shortx8*)(&hbuf[(tt * 16 + l15) * 520 + kt * 32 + q * 8]);
#pragma unroll
            for (int nt = 0; nt < 6; ++nt) {
                shortx8 wf = *(const shortx8*)(w3p + ((w * 18 + gi * 6 + nt) * 16 + kt) * 512 + lane * 8);
#pragma unroll
                for (int tt = 0; tt < 2; ++tt)
                    acc[tt][nt] = __builtin_amdgcn_mfma_f32_16x16x32_bf16(wf, hb[tt], acc[tt][nt], 0, 0, 0);
            }
        }
        // Store: per (wave,gi) 96 contiguous cols = 384 B per token row,
        // starting at byte w*1152 + gi*384 -> whole 128B lines, no partials.
#pragma unroll
        for (int nt = 0; nt < 6; ++nt) {
            const int colb = (w * 18 + gi * 6 + nt) * 16 + q * 4;
            const floatx4 bias = *(const floatx4*)(b3 + colb);
#pragma unroll
            for (int tt = 0; tt < 2; ++tt) {
                floatx4 v = acc[tt][nt] + bias;
                __builtin_nontemporal_store(
                    v, (floatx4*)(out + (size_t)(m0 + tt * 16 + l15) * 1152 + colb));
            }
        }
    }
}

extern "C" void kernel_launch(void* const* d_in, const int* in_sizes, int n_in,
                              void* d_out, int out_size, void* d_ws, size_t ws_size,
                              hipStream_t stream) {
    const float* content = (const float*)d_in[0];  // [64,256]
    const float* motion  = (const float*)d_in[1];  // [64,512,128]
    const float* W1 = (const float*)d_in[2];       // [384,256]
    const float* b1 = (const float*)d_in[3];
    const float* W2 = (const float*)d_in[4];       // [256,512]
    const float* b2 = (const float*)d_in[5];
    const float* W3 = (const float*)d_in[6];       // [512,1152]
    const float* b3 = (const float*)d_in[7];
    float* out = (float*)d_out;

    short* ws  = (short*)d_ws;
    short* w1p = ws;                     // 192 tiles * 512 elems
    short* w2p = ws + 98304;             // 256 tiles * 512
    short* w3p = ws + 98304 + 131072;    // 1152 tiles * 512

    repack_all<<<400, 256, 0, stream>>>(W1, W2, W3, ws);
    fused_mlp<<<1024, 256, 0, stream>>>(content, motion, b1, b2, b3,
                                        w1p, w2p, w3p, out);
}

// Round 3
// 236.038 us; speedup vs baseline: 1.0802x; 1.0802x over previous
//
#include <hip/hip_runtime.h>

// I/O: float32 (per reference). Internal compute: bf16 MFMA (2%-relative
// threshold; measured absmax 0.0156 vs 0.0615 budget in R2/R3).
//
// R7: maximize MFMA-per-weight-load. R6 post-mortem: occupancy UP (42%) but
// 38% SLOWER than R5 -- occupancy was never binding. The moved variable was
// MFMAs per L2 weight-fragment load: R5 tt=4 (4:1, 0.82GB wgt traffic,
// 92.6us) vs R6 tt=2 (2:1, 1.64GB, 128us) -- wall tracks weight-load count
// while all pipes <25% busy => L2 weight-load latency/traffic bound.
// Now tt=8: 128-token blocks, 512 thr, grid=256 (1 block/CU), 0.41GB weight
// traffic (12us L2 floor), 8 MFMAs per fragment. Column ownership per wave
// IDENTICAL to proven R5; only tt/LDS-rows/grid/bidx change. LDS 133KB ->
// 2 waves/SIMD; launch_bounds(512,2) frees regs to 256 so acc[8][4]=128
// AGPRs + fragments fit and compiler can pipeline deep. Stores: plain (not
// nontemporal) -- R6 showed WRITE 206MB vs 151 ideal with NT; testing
// whether NT's early eviction is the amplifier.

typedef __attribute__((ext_vector_type(4))) float  floatx4;
typedef __attribute__((ext_vector_type(8))) short  shortx8;
typedef __attribute__((ext_vector_type(4))) short  shortx4;

__device__ __forceinline__ short f2bf(float f) {
    unsigned u = __builtin_bit_cast(unsigned, f);
    u += 0x7fffu + ((u >> 16) & 1u);   // RTNE
    return (short)(u >> 16);
}

__device__ __forceinline__ shortx8 cvt8(const float* __restrict__ p) {
    floatx4 a = *(const floatx4*)p;
    floatx4 b = *(const floatx4*)(p + 4);
    shortx8 r;
    r[0] = f2bf(a[0]); r[1] = f2bf(a[1]); r[2] = f2bf(a[2]); r[3] = f2bf(a[3]);
    r[4] = f2bf(b[0]); r[5] = f2bf(b[1]); r[6] = f2bf(b[2]); r[7] = f2bf(b[3]);
    return r;
}

// Single-launch repack of W1/W2/W3 (f32 row-major [K,N]) into bf16 MFMA
// fragment order. Tile rel=(nt*KT+kt): lane l holds
// W[kt*32+(l>>4)*8+j][nt*16+(l&15)], j=0..7, 16B contiguous per lane.
// (Used as the A operand: mfma(w_frag, x_frag) computes the transposed tile,
// so D reg index runs along contiguous output columns.)
__global__ void repack_all(const float* __restrict__ W1,
                           const float* __restrict__ W2,
                           const float* __restrict__ W3,
                           short* __restrict__ ws) {
    int t = blockIdx.x * blockDim.x + threadIdx.x;
    int tile = t >> 6, lane = t & 63;
    const float* src; short* dst; int N, KT, rel;
    if (tile < 192)       { src = W1; dst = ws;                  N = 256;  KT = 12; rel = tile; }
    else if (tile < 448)  { src = W2; dst = ws + 98304;          N = 512;  KT = 8;  rel = tile - 192; }
    else if (tile < 1600) { src = W3; dst = ws + 98304 + 131072; N = 1152; KT = 16; rel = tile - 448; }
    else return;
    int nt = rel / KT, kt = rel - nt * KT;
    int col  = nt * 16 + (lane & 15);
    int row0 = kt * 32 + (lane >> 4) * 8;
    shortx8 v;
#pragma unroll
    for (int j = 0; j < 8; ++j) v[j] = f2bf(src[(row0 + j) * N + col]);
    *(shortx8*)(dst + rel * 512 + lane * 8) = v;
}

__global__ __launch_bounds__(512, 2) void fused_mlp(
    const float* __restrict__ content, const float* __restrict__ motion,
    const float* __restrict__ b1, const float* __restrict__ b2,
    const float* __restrict__ b3,
    const short* __restrict__ w1p, const short* __restrict__ w2p,
    const short* __restrict__ w3p, float* __restrict__ out)
{
    __shared__ short hbuf[128 * 520];  // 133,120 B: h2 view stride 520; h1 view stride 264

    const int tid  = threadIdx.x;
    const int lane = tid & 63;
    const int w    = tid >> 6;        // wave 0..7: output-column-strip owner
    const int l15  = lane & 15;
    const int q    = lane >> 4;       // 0..3
    const int m0   = blockIdx.x * 128;
    const int bidx = blockIdx.x >> 2; // batch element (4 blocks per batch row)

    // ---------------- Layer 1: X[128,384] @ W1 -> h1[128,256] ----------------
    {
        floatx4 accC[2]    = {};      // content contribution (token-independent)
        floatx4 accM[8][2] = {};      // motion contribution per token tile
        const float* crow = content + bidx * 256;
        // content half: k = 0..255, computed ONCE (identical for all tokens)
#pragma unroll
        for (int kt = 0; kt < 8; ++kt) {
            shortx8 xb = cvt8(crow + kt * 32 + q * 8);
#pragma unroll
            for (int nt = 0; nt < 2; ++nt) {
                shortx8 wf = *(const shortx8*)(w1p + ((w * 2 + nt) * 12 + kt) * 512 + lane * 8);
                accC[nt] = __builtin_amdgcn_mfma_f32_16x16x32_bf16(wf, xb, accC[nt], 0, 0, 0);
            }
        }
        // motion half: k = 256..383
#pragma unroll
        for (int kt = 8; kt < 12; ++kt) {
            shortx8 xb[8];
#pragma unroll
            for (int tt = 0; tt < 8; ++tt)
                xb[tt] = cvt8(motion + (m0 + tt * 16 + l15) * 128 + (kt * 32 - 256) + q * 8);
#pragma unroll
            for (int nt = 0; nt < 2; ++nt) {
                shortx8 wf = *(const shortx8*)(w1p + ((w * 2 + nt) * 12 + kt) * 512 + lane * 8);
#pragma unroll
                for (int tt = 0; tt < 8; ++tt)
                    accM[tt][nt] = __builtin_amdgcn_mfma_f32_16x16x32_bf16(wf, xb[tt], accM[tt][nt], 0, 0, 0);
            }
        }
#pragma unroll
        for (int nt = 0; nt < 2; ++nt) {
            const int colb = (w * 2 + nt) * 16 + q * 4;
            const floatx4 bias = *(const floatx4*)(b1 + colb);
#pragma unroll
            for (int tt = 0; tt < 8; ++tt) {
                shortx4 pk;
#pragma unroll
                for (int r = 0; r < 4; ++r) {
                    float v = accM[tt][nt][r] + accC[nt][r] + bias[r];
                    v = (v >= 0.f) ? v : 0.2f * v;
                    pk[r] = f2bf(v);
                }
                *(shortx4*)(&hbuf[(tt * 16 + l15) * 264 + colb]) = pk;  // 8B ds_write
            }
        }
    }
    __syncthreads();

    // ---------------- Layer 2: h1[128,256] @ W2 -> h2[128,512] ----------------
    {
        floatx4 acc[8][4] = {};
#pragma unroll
        for (int kt = 0; kt < 8; ++kt) {
            shortx8 hb[8];
#pragma unroll
            for (int tt = 0; tt < 8; ++tt)
                hb[tt] = *(const shortx8*)(&hbuf[(tt * 16 + l15) * 264 + kt * 32 + q * 8]);
#pragma unroll
            for (int nt = 0; nt < 4; ++nt) {
                shortx8 wf = *(const shortx8*)(w2p + ((w * 4 + nt) * 8 + kt) * 512 + lane * 8);
#pragma unroll
                for (int tt = 0; tt < 8; ++tt)
                    acc[tt][nt] = __builtin_amdgcn_mfma_f32_16x16x32_bf16(wf, hb[tt], acc[tt][nt], 0, 0, 0);
            }
        }
        __syncthreads();   // all h1 reads complete before h2 overwrites buffer
#pragma unroll
        for (int nt = 0; nt < 4; ++nt) {
            const int colb = (w * 4 + nt) * 16 + q * 4;
            const floatx4 bias = *(const floatx4*)(b2 + colb);
#pragma unroll
            for (int tt = 0; tt < 8; ++tt) {
                shortx4 pk;
#pragma unroll
                for (int r = 0; r < 4; ++r) {
                    float v = acc[tt][nt][r] + bias[r];
                    v = (v >= 0.f) ? v : 0.2f * v;
                    pk[r] = f2bf(v);
                }
                *(shortx4*)(&hbuf[(tt * 16 + l15) * 520 + colb]) = pk;  // 8B ds_write
            }
        }
    }
    __syncthreads();

    // ----- Layer 3: h2[128,512] @ W3 -> out[128,1152], 3 passes of 48 cols/wave -----
#pragma unroll 1
    for (int gi = 0; gi < 3; ++gi) {
        floatx4 acc[8][3] = {};   // 96 accs
#pragma unroll 4
        for (int kt = 0; kt < 16; ++kt) {
            shortx8 hb[8];
#pragma unroll
            for (int tt = 0; tt < 8; ++tt)
                hb[tt] = *(const shortx8*)(&hbuf[(tt * 16 + l15) * 520 + kt * 32 + q * 8]);
#pragma unroll
            for (int nt = 0; nt < 3; ++nt) {
                shortx8 wf = *(const shortx8*)(w3p + ((w * 9 + gi * 3 + nt) * 16 + kt) * 512 + lane * 8);
#pragma unroll
                for (int tt = 0; tt < 8; ++tt)
                    acc[tt][nt] = __builtin_amdgcn_mfma_f32_16x16x32_bf16(wf, hb[tt], acc[tt][nt], 0, 0, 0);
            }
        }
#pragma unroll
        for (int nt = 0; nt < 3; ++nt) {
            const int colb = (w * 9 + gi * 3 + nt) * 16 + q * 4;
            const floatx4 bias = *(const floatx4*)(b3 + colb);
#pragma unroll
            for (int tt = 0; tt < 8; ++tt) {
                floatx4 v = acc[tt][nt] + bias;
                *(floatx4*)(out + (size_t)(m0 + tt * 16 + l15) * 1152 + colb) = v;
            }
        }
    }
}

extern "C" void kernel_launch(void* const* d_in, const int* in_sizes, int n_in,
                              void* d_out, int out_size, void* d_ws, size_t ws_size,
                              hipStream_t stream) {
    const float* content = (const float*)d_in[0];  // [64,256]
    const float* motion  = (const float*)d_in[1];  // [64,512,128]
    const float* W1 = (const float*)d_in[2];       // [384,256]
    const float* b1 = (const float*)d_in[3];
    const float* W2 = (const float*)d_in[4];       // [256,512]
    const float* b2 = (const float*)d_in[5];
    const float* W3 = (const float*)d_in[6];       // [512,1152]
    const float* b3 = (const float*)d_in[7];
    float* out = (float*)d_out;

    short* ws  = (short*)d_ws;
    short* w1p = ws;                     // 192 tiles * 512 elems
    short* w2p = ws + 98304;             // 256 tiles * 512
    short* w3p = ws + 98304 + 131072;    // 1152 tiles * 512

    repack_all<<<400, 256, 0, stream>>>(W1, W2, W3, ws);
    fused_mlp<<<256, 512, 0, stream>>>(content, motion, b1, b2, b3,
                                       w1p, w2p, w3p, out);
}